// Round 2
// baseline (660.618 us; speedup 1.0000x reference)
//
#include <hip/hip_runtime.h>
#include <stdint.h>
#include <math.h>

typedef unsigned long long ull;
typedef __attribute__((ext_vector_type(8))) short short8;
typedef __attribute__((ext_vector_type(4))) float f32x4;

#define DD 20000
#define NK 64
#define NB 4096
#define YN (NB * NK)              // 262144
#define TOTN (YN + NK * DD + 1)   // 1542145
#define KS 15                     // split-K factor (64 rows + 960 gemm = 1024 blocks)

// ws byte offsets
#define E_OFF   0u                 // f64 e = exp(z) [64][20000]
#define RSP_OFF 10240000u          // f64 row partial sums [313][64]
#define CV_OFF  10400256u          // f32 top-64 vals [64][64]
#define CC_OFF  10416640u          // i32 top-64 cols [64][64]
#define EB_OFF  10433024u          // bf16 e [64][20000] (ushort)
#define IRS_OFF 12993024u          // f32 1/rowsum [64]
#define P_OFF   12993280u          // f32 GEMM partials [KS][4096][64]
#define CNT_OFF 28721920u          // i32 counters: [0..63]=by_done, [64]=rows_done

// dynamic LDS: rows (redd 2K | keys 16K | wbest) then greedy (vf 16K | cf 16K | usedw 2.5K)
#define DSM_BYTES 35328

// ---------------- threefry2x32, JAX partitionable scheme ----------------
__device__ __forceinline__ uint32_t tf_bits(uint32_t j) {
  const uint32_t k0 = 0u, k1 = 42u;
  const uint32_t k2 = 0x1BD11BDAu ^ k0 ^ k1;
  uint32_t x0 = k0;
  uint32_t x1 = j + k1;
#define TFR(r) { x0 += x1; x1 = (x1 << r) | (x1 >> (32 - r)); x1 ^= x0; }
  TFR(13) TFR(15) TFR(26) TFR(6)
  x0 += k1; x1 += k2 + 1u;
  TFR(17) TFR(29) TFR(16) TFR(24)
  x0 += k2; x1 += k0 + 2u;
  TFR(13) TFR(15) TFR(26) TFR(6)
  x0 += k0; x1 += k1 + 3u;
  TFR(17) TFR(29) TFR(16) TFR(24)
  x0 += k1; x1 += k2 + 4u;
  TFR(13) TFR(15) TFR(26) TFR(6)
  x0 += k2; x1 += k0 + 5u;
#undef TFR
  return x0 ^ x1;
}

// ---------------- K1: e = exp((log(10*clip(sm64(u@W))) + gumbel)/nt) --------
// Unchanged math. Also zeroes the mega-kernel's device counters (ws is
// re-poisoned every iteration, and k_z completes before k_mega by stream order).
__global__ __launch_bounds__(256) void k_z(
    const float* __restrict__ uu, const float* __restrict__ tw,
    const float* __restrict__ temp, double* __restrict__ E,
    ushort* __restrict__ EB, double* __restrict__ RSP,
    float* __restrict__ disc, int* __restrict__ CNT) {
  __shared__ double tile[NK][65];   // [k][dl], +1 pad
  __shared__ double psumw[4][NK];
  const int tid = threadIdx.x;
  if (blockIdx.x == 0 && tid < 65) CNT[tid] = 0;
  const int lane = tid & 63;      // = k
  const int wv = tid >> 6;
  const int d0 = blockIdx.x * 64;
  const float nt = fmaxf(0.1f, temp[0] * 0.99999f);
  float w[10];
#pragma unroll
  for (int i = 0; i < 10; ++i) w[i] = tw[i * NK + lane];
  double psum = 0.0;
  for (int it = 0; it < 16; ++it) {
    const int dl = wv * 16 + it;
    const int d = d0 + dl;
    double e = 0.0;
    if (d < DD) {  // wave-uniform branch
      float m = 0.f;
#pragma unroll
      for (int i = 0; i < 10; ++i) m = fmaf(uu[d * 10 + i], w[i], m);
      float mx = m;
#pragma unroll
      for (int off = 32; off; off >>= 1) mx = fmaxf(mx, __shfl_xor(mx, off, 64));
      double ee = exp((double)(m - mx));
      double ssum = ee;
#pragma unroll
      for (int off = 32; off; off >>= 1) ssum += __shfl_xor(ssum, off, 64);
      float al = (float)(ee / ssum);
      float c = fminf(fmaxf(al, 1e-7f), 0.9999999f);
      float lg = (float)log((double)(10.0f * c));
      const uint32_t bits = tf_bits((uint32_t)(lane * DD + d));
      float uf = __uint_as_float((bits >> 9) | 0x3f800000u) - 1.0f;
      float uv = fmaxf(1e-7f, uf * (1.0f - 1e-7f) + 1e-7f);
      float g = (float)(-log(-log((double)uv)));
      float z = (lg + g) / nt;     // z in [-1.7, 1.9] -> no max-sub needed
      e = exp((double)z);
    }
    tile[lane][dl] = e;
    psum += e;
  }
  psumw[wv][lane] = psum;
  __syncthreads();
  for (int r0 = 0; r0 < NK; r0 += 4) {
    const int r = r0 + wv;
    const int d = d0 + lane;
    if (d < DD) {
      const double ev = tile[r][lane];
      E[(size_t)r * DD + d] = ev;
      const float ef = (float)ev;
      uint32_t ub = __float_as_uint(ef);
      EB[(size_t)r * DD + d] = (ushort)((ub + 0x7FFFu + ((ub >> 16) & 1u)) >> 16);
    }
  }
  if (wv == 0) {
    double s = psumw[0][lane] + psumw[1][lane] + psumw[2][lane] + psumw[3][lane];
    RSP[(size_t)blockIdx.x * NK + lane] = s;
  }
  // zero the discrete slice: cols [d0, d0+64) x 64 rows, float4 stores
  const int cg = tid & 15;         // col group (4 cols)
  const int r0 = tid >> 4;         // 0..15
  if (d0 + cg * 4 < DD) {
    for (int r = r0; r < NK; r += 16)
      *(float4*)(disc + (size_t)r * DD + d0 + cg * 4) = make_float4(0.f, 0.f, 0.f, 0.f);
  }
}

// ---------------- K2: mega — rows(0..63, last one runs greedy) + GEMM(64..1023,
// last ksp-finisher per by does the Y reduction). Exactly 1024 blocks = one
// dispatch generation at 4 blocks/CU (LDS 34.5K dyn, VGPR capped 128).
__global__ __launch_bounds__(256, 4) void k_mega(
    const float* __restrict__ X, const ushort* __restrict__ EB,
    float* __restrict__ P,
    const double* __restrict__ E, const double* __restrict__ RSP,
    float* __restrict__ cv, int* __restrict__ cc, float* __restrict__ invRS,
    const float* __restrict__ temp, float* __restrict__ out,
    int* __restrict__ CNT) {
  extern __shared__ char sm[];
  __shared__ int sflag;
  const int tid = threadIdx.x;

  if (blockIdx.x < 64) {
    // ---- rows: row sums + exact top-64 (identical math to before) ----
    const int k = blockIdx.x;
    double* redd = (double*)sm;                 // 2048 B
    ull* keys = (ull*)(sm + 2048);              // 16384 B
    ull* wbest = (ull*)(sm + 18432);            // 32 B
    const double* er = E + (size_t)k * DD;
    double psum = 0.0;
    for (int b = tid; b < 313; b += 256) psum += RSP[(size_t)b * NK + k];
    redd[tid] = psum;
    __syncthreads();
    for (int s = 128; s; s >>= 1) {
      if (tid < s) redd[tid] += redd[tid + s];
      __syncthreads();
    }
    const double sumall = redd[0];
    if (tid == 0) invRS[k] = (float)(1.0 / sumall);
    float tv[8]; int tc[8];
#pragma unroll
    for (int s = 0; s < 8; ++s) { tv[s] = -1.f; tc[s] = 0; }
    for (int d = tid; d < DD; d += 256) {
      float svv = (float)(er[d] / sumall);   // same bits as samples (f32)
      if (svv > tv[7]) {
        float cvr = svv; int ccr = d;
#pragma unroll
        for (int s = 0; s < 8; ++s) {
          bool sw = cvr > tv[s];
          float nv = sw ? cvr : tv[s]; int nc = sw ? ccr : tc[s];
          cvr = sw ? tv[s] : cvr; ccr = sw ? tc[s] : ccr;
          tv[s] = nv; tc[s] = nc;
        }
      }
    }
#pragma unroll
    for (int s = 0; s < 8; ++s)
      keys[(tid << 3) + s] = (((ull)__float_as_uint(tv[s])) << 32)
                           | ((ull)(uint32_t)(32767 - tc[s]) << 11)
                           | ((ull)tid << 3) | (ull)s;
    __syncthreads();
    for (int t = 0; t < NK; ++t) {
      ull best = 0;
#pragma unroll
      for (int s = 0; s < 8; ++s) { ull kk = keys[(tid << 3) + s]; if (kk > best) best = kk; }
#pragma unroll
      for (int off = 32; off; off >>= 1) { ull o = __shfl_xor(best, off, 64); if (o > best) best = o; }
      if ((tid & 63) == 0) wbest[tid >> 6] = best;
      __syncthreads();
      ull win = wbest[0];
#pragma unroll
      for (int wI = 1; wI < 4; ++wI) if (wbest[wI] > win) win = wbest[wI];
      const uint32_t lo = (uint32_t)win;
      const int slot = lo & 7;
      const int owner = (lo >> 3) & 255;
      const int col = 32767 - (int)(lo >> 11);
      if (tid == 0) {
        cv[(k << 6) + t] = __uint_as_float((uint32_t)(win >> 32));
        cc[(k << 6) + t] = col;
      }
      if (tid == owner) keys[(owner << 3) + slot] = 0;
      __syncthreads();
    }
    // ---- completion: last rows block runs the greedy assignment ----
    if (tid == 0) {
      int old = __hip_atomic_fetch_add(&CNT[64], 1, __ATOMIC_ACQ_REL,
                                       __HIP_MEMORY_SCOPE_AGENT);
      sflag = (old == 63);
    }
    __syncthreads();
    if (!sflag) return;
    __threadfence();               // acquire: invalidate stale lines (cross-XCD cv/cc)
    float* vf = (float*)sm;                    // 16384 B (overlays redd/keys)
    int* cf = (int*)(sm + 16384);              // 16384 B
    uint32_t* usedw = (uint32_t*)(sm + 32768); // 2500 B bitmask over DD cols
    for (int i = tid; i < 625; i += 256) usedw[i] = 0;
    for (int i = tid; i < 1024; i += 256) {
      ((float4*)vf)[i] = ((const float4*)cv)[i];
      ((int4*)cf)[i] = ((const int4*)cc)[i];
    }
    __syncthreads();
    if (tid >= 64) return;          // wave 0 only past this point (no barriers)
    const int lane = tid;           // = row k
    int ptr = 0;
    float hv = vf[lane << 6];       // current head (row's best unused col)
    int hc = cf[lane << 6];
    bool done = false;
    for (int t = 0; t < NK; ++t) {
      const float v = done ? -1.f : hv;
      float m = v;
#pragma unroll
      for (int off = 32; off; off >>= 1) m = fmaxf(m, __shfl_xor(m, off, 64));
      const ull mask = __ballot(v == m);         // ties -> smallest row wins
      const int row = __ffsll(mask) - 1;         // == flat-argmax tie-break
      const int col = __shfl(hc, row, 64);
      if (lane == row) done = true;
      if (lane == 0) {
        usedw[col >> 5] |= (1u << (col & 31));
        out[YN + (size_t)row * DD + col] = 1.0f;
      }
      asm volatile("s_waitcnt lgkmcnt(0)" ::: "memory");  // usedw visible in-wave
      if (!done && hc == col) {     // advance past used cols (lazy skip)
        ++ptr;
        while (ptr < NK) {
          hc = cf[(lane << 6) + ptr];
          if (!((usedw[hc >> 5] >> (hc & 31)) & 1u)) break;
          ++ptr;
        }
        if (ptr < NK) hv = vf[(lane << 6) + ptr];
        else { hv = -2.f; hc = 0; } // exhausted (cannot occur in practice)
      }
    }
    if (lane == 0) out[TOTN - 1] = fmaxf(0.1f, temp[0] * 0.99999f);
    return;
  }

  // ---- GEMM: P[ksp] = X @ bf16(e)^T, 16x16x32 bf16 MFMA, 2-deep prefetch ----
  const int bx2 = blockIdx.x - 64;
  const int ksp = bx2 >> 6;         // ksp-major: 64 consecutive blocks share EB slice
  const int by = bx2 & 63;
  const int lane = tid & 63;
  const int wv = tid >> 6;
  const int m16 = lane & 15;
  const int kq = lane >> 4;         // 0..3
  const float* xq = X + (size_t)(by * 64 + wv * 16 + m16) * DD + ksp * 32 + kq * 8;
  const ushort* bq = EB + (size_t)m16 * DD + ksp * 32 + kq * 8;
  f32x4 acc[4] = {{0,0,0,0},{0,0,0,0},{0,0,0,0},{0,0,0,0}};
  const int jN = (625 - ksp + KS - 1) / KS;   // 42 for ksp<=9, 41 for ksp>=10

#define LOADBUF(xa, xb, bn, j) { \
    const int o_ = (j) * (KS * 32); \
    xa = *(const float4*)(xq + o_); \
    xb = *(const float4*)(xq + o_ + 4); \
    bn##0 = *(const uint4*)(bq + o_); \
    bn##1 = *(const uint4*)(bq + 16 * DD + o_); \
    bn##2 = *(const uint4*)(bq + 32 * DD + o_); \
    bn##3 = *(const uint4*)(bq + 48 * DD + o_); }

#define COMPUTEBUF(xa, xb, bn) { \
    uint32_t t0=__float_as_uint(xa.x), t1=__float_as_uint(xa.y), t2=__float_as_uint(xa.z), t3=__float_as_uint(xa.w); \
    uint32_t t4=__float_as_uint(xb.x), t5=__float_as_uint(xb.y), t6=__float_as_uint(xb.z), t7=__float_as_uint(xb.w); \
    t0=(t0+0x7FFFu+((t0>>16)&1u))>>16; t1=(t1+0x7FFFu+((t1>>16)&1u))>>16; \
    t2=(t2+0x7FFFu+((t2>>16)&1u))>>16; t3=(t3+0x7FFFu+((t3>>16)&1u))>>16; \
    t4=(t4+0x7FFFu+((t4>>16)&1u))>>16; t5=(t5+0x7FFFu+((t5>>16)&1u))>>16; \
    t6=(t6+0x7FFFu+((t6>>16)&1u))>>16; t7=(t7+0x7FFFu+((t7>>16)&1u))>>16; \
    union { uint32_t u[4]; short8 v; } A_; \
    A_.u[0]=t0|(t1<<16); A_.u[1]=t2|(t3<<16); A_.u[2]=t4|(t5<<16); A_.u[3]=t6|(t7<<16); \
    union { uint4 q; short8 v; } Q0_, Q1_, Q2_, Q3_; \
    Q0_.q = bn##0; Q1_.q = bn##1; Q2_.q = bn##2; Q3_.q = bn##3; \
    acc[0] = __builtin_amdgcn_mfma_f32_16x16x32_bf16(A_.v, Q0_.v, acc[0], 0, 0, 0); \
    acc[1] = __builtin_amdgcn_mfma_f32_16x16x32_bf16(A_.v, Q1_.v, acc[1], 0, 0, 0); \
    acc[2] = __builtin_amdgcn_mfma_f32_16x16x32_bf16(A_.v, Q2_.v, acc[2], 0, 0, 0); \
    acc[3] = __builtin_amdgcn_mfma_f32_16x16x32_bf16(A_.v, Q3_.v, acc[3], 0, 0, 0); }

  float4 xaA, xbA, xaB, xbB;
  uint4 bA0, bA1, bA2, bA3, bB0, bB1, bB2, bB3;
  LOADBUF(xaA, xbA, bA, 0);        // jN >= 41, so j = 0,1 always valid
  LOADBUF(xaB, xbB, bB, 1);
  int j = 0;
  for (; j + 2 < jN; j += 2) {
    COMPUTEBUF(xaA, xbA, bA);
    LOADBUF(xaA, xbA, bA, j + 2);
    COMPUTEBUF(xaB, xbB, bB);
    if (j + 3 < jN) { LOADBUF(xaB, xbB, bB, j + 3); }
  }
  COMPUTEBUF(xaA, xbA, bA);
  if (j + 1 < jN) { COMPUTEBUF(xaB, xbB, bB); }
#undef LOADBUF
#undef COMPUTEBUF

  {
    float* pp = P + (size_t)ksp * YN;
    const int rBase = by * 64 + wv * 16 + kq * 4;
#pragma unroll
    for (int nt = 0; nt < 4; ++nt)
#pragma unroll
      for (int r = 0; r < 4; ++r)
        pp[(size_t)(rBase + r) * 64 + nt * 16 + m16] = acc[nt][r];
  }
  __syncthreads();                 // all 4 waves' P stores drained to L2
  if (tid == 0) {
    int old = __hip_atomic_fetch_add(&CNT[by], 1, __ATOMIC_ACQ_REL,
                                     __HIP_MEMORY_SCOPE_AGENT);
    sflag = (old == KS - 1);       // last ksp-finisher for this by-tile
  }
  __syncthreads();
  if (!sflag) return;
  __threadfence();                 // acquire: other XCDs' P slabs + invRS
  // invRS must be released (rows_done == 64); in practice long done by now.
  while (__hip_atomic_load(&CNT[64], __ATOMIC_ACQUIRE, __HIP_MEMORY_SCOPE_AGENT) < 64)
    __builtin_amdgcn_s_sleep(2);
  // Y[by-tile] = (sum_j P[j]) * invRS[col] — j ascending, same order as before.
  for (int q = tid; q < 1024; q += 256) {
    const int row = q >> 4;        // 0..63
    const int c4 = q & 15;         // float4 index over the 64 cols
    const size_t idx = (size_t)(by * 64 + row) * 16 + c4;
    float4 a = ((const float4*)P)[idx];
#pragma unroll
    for (int jj = 1; jj < KS; ++jj) {
      const float4 b = ((const float4*)(P + (size_t)jj * YN))[idx];
      a.x += b.x; a.y += b.y; a.z += b.z; a.w += b.w;
    }
    const float4 irs = ((const float4*)invRS)[c4];
    a.x *= irs.x; a.y *= irs.y; a.z *= irs.z; a.w *= irs.w;
    ((float4*)out)[idx] = a;
  }
}

extern "C" void kernel_launch(void* const* d_in, const int* in_sizes, int n_in,
                              void* d_out, int out_size, void* d_ws, size_t ws_size,
                              hipStream_t stream) {
  (void)in_sizes; (void)n_in; (void)out_size; (void)ws_size;
  const float* X = (const float*)d_in[0];
  const float* uu = (const float*)d_in[1];
  const float* tw = (const float*)d_in[2];
  const float* temp = (const float*)d_in[3];
  float* out = (float*)d_out;
  char* W = (char*)d_ws;
  double* E   = (double*)(W + E_OFF);
  double* RSP = (double*)(W + RSP_OFF);
  float*  CV  = (float*)(W + CV_OFF);
  int*    CC  = (int*)(W + CC_OFF);
  ushort* EB  = (ushort*)(W + EB_OFF);
  float*  IRS = (float*)(W + IRS_OFF);
  float*  P   = (float*)(W + P_OFF);
  int*    CNT = (int*)(W + CNT_OFF);

  hipLaunchKernelGGL(k_z, dim3(313), dim3(256), 0, stream,
                     uu, tw, temp, E, EB, RSP, out + YN, CNT);
  hipLaunchKernelGGL(k_mega, dim3(1024), dim3(256), DSM_BYTES, stream,
                     X, EB, P, E, RSP, CV, CC, IRS, temp, out, CNT);
}

// Round 3
// 559.128 us; speedup vs baseline: 1.1815x; 1.1815x over previous
//
#include <hip/hip_runtime.h>
#include <stdint.h>
#include <math.h>

typedef unsigned long long ull;
typedef __attribute__((ext_vector_type(8))) short short8;
typedef __attribute__((ext_vector_type(4))) float f32x4;

#define DD 20000
#define NK 64
#define NB 4096
#define YN (NB * NK)              // 262144
#define TOTN (YN + NK * DD + 1)   // 1542145
#define KS 16                     // split-K factor for the GEMM

// ws byte offsets (~29.8 MB used)
#define E_OFF   0u                 // f64 e = exp(z) [64][20000]
#define RSP_OFF 10240000u          // f64 row partial sums [313][64]
#define CV_OFF  10400256u          // f32 top-64 vals [64][64]
#define CC_OFF  10416640u          // i32 top-64 cols [64][64]
#define EB_OFF  10433024u          // bf16 e [64][20000] (ushort)
#define IRS_OFF 12993024u          // f32 1/rowsum [64]
#define P_OFF   12993280u          // f32 GEMM partials [KS][4096][64]

// ---------------- threefry2x32, JAX partitionable scheme ----------------
__device__ __forceinline__ uint32_t tf_bits(uint32_t j) {
  const uint32_t k0 = 0u, k1 = 42u;
  const uint32_t k2 = 0x1BD11BDAu ^ k0 ^ k1;
  uint32_t x0 = k0;
  uint32_t x1 = j + k1;
#define TFR(r) { x0 += x1; x1 = (x1 << r) | (x1 >> (32 - r)); x1 ^= x0; }
  TFR(13) TFR(15) TFR(26) TFR(6)
  x0 += k1; x1 += k2 + 1u;
  TFR(17) TFR(29) TFR(16) TFR(24)
  x0 += k2; x1 += k0 + 2u;
  TFR(13) TFR(15) TFR(26) TFR(6)
  x0 += k0; x1 += k1 + 3u;
  TFR(17) TFR(29) TFR(16) TFR(24)
  x0 += k1; x1 += k2 + 4u;
  TFR(13) TFR(15) TFR(26) TFR(6)
  x0 += k2; x1 += k0 + 5u;
#undef TFR
  return x0 ^ x1;
}

// ---------------- K1: e = exp((log(10*clip(sm64(u@W))) + gumbel)/nt) --------
__global__ __launch_bounds__(256) void k_z(
    const float* __restrict__ uu, const float* __restrict__ tw,
    const float* __restrict__ temp, double* __restrict__ E,
    ushort* __restrict__ EB, double* __restrict__ RSP,
    float* __restrict__ disc) {
  __shared__ double tile[NK][65];   // [k][dl], +1 pad
  __shared__ double psumw[4][NK];
  const int tid = threadIdx.x;
  const int lane = tid & 63;      // = k
  const int wv = tid >> 6;
  const int d0 = blockIdx.x * 64;
  const float nt = fmaxf(0.1f, temp[0] * 0.99999f);
  float w[10];
#pragma unroll
  for (int i = 0; i < 10; ++i) w[i] = tw[i * NK + lane];
  double psum = 0.0;
  for (int it = 0; it < 16; ++it) {
    const int dl = wv * 16 + it;
    const int d = d0 + dl;
    double e = 0.0;
    if (d < DD) {  // wave-uniform branch
      float m = 0.f;
#pragma unroll
      for (int i = 0; i < 10; ++i) m = fmaf(uu[d * 10 + i], w[i], m);
      float mx = m;
#pragma unroll
      for (int off = 32; off; off >>= 1) mx = fmaxf(mx, __shfl_xor(mx, off, 64));
      double ee = exp((double)(m - mx));
      double ssum = ee;
#pragma unroll
      for (int off = 32; off; off >>= 1) ssum += __shfl_xor(ssum, off, 64);
      float al = (float)(ee / ssum);
      float c = fminf(fmaxf(al, 1e-7f), 0.9999999f);
      float lg = (float)log((double)(10.0f * c));
      const uint32_t bits = tf_bits((uint32_t)(lane * DD + d));
      float uf = __uint_as_float((bits >> 9) | 0x3f800000u) - 1.0f;
      float uv = fmaxf(1e-7f, uf * (1.0f - 1e-7f) + 1e-7f);
      float g = (float)(-log(-log((double)uv)));
      float z = (lg + g) / nt;     // z in [-1.7, 1.9] -> no max-sub needed
      e = exp((double)z);
    }
    tile[lane][dl] = e;
    psum += e;
  }
  psumw[wv][lane] = psum;
  __syncthreads();
  for (int r0 = 0; r0 < NK; r0 += 4) {
    const int r = r0 + wv;
    const int d = d0 + lane;
    if (d < DD) {
      const double ev = tile[r][lane];
      E[(size_t)r * DD + d] = ev;
      const float ef = (float)ev;
      uint32_t ub = __float_as_uint(ef);
      EB[(size_t)r * DD + d] = (ushort)((ub + 0x7FFFu + ((ub >> 16) & 1u)) >> 16);
    }
  }
  if (wv == 0) {
    double s = psumw[0][lane] + psumw[1][lane] + psumw[2][lane] + psumw[3][lane];
    RSP[(size_t)blockIdx.x * NK + lane] = s;
  }
  // zero the discrete slice: cols [d0, d0+64) x 64 rows, float4 stores
  const int cg = tid & 15;         // col group (4 cols)
  const int r0 = tid >> 4;         // 0..15
  if (d0 + cg * 4 < DD) {
    for (int r = r0; r < NK; r += 16)
      *(float4*)(disc + (size_t)r * DD + d0 + cg * 4) = make_float4(0.f, 0.f, 0.f, 0.f);
  }
}

// ---------------- K2: fused rows (blocks 0..63) + split-K GEMM (64..1087) ---
// Round-1 structure (proven codegen: deep prefetch kept in registers).
// Single change vs round 1: prefetch depth 3 -> 4 (24 loads in flight/wave).
__global__ __launch_bounds__(256) void k_gr(
    const float* __restrict__ X, const ushort* __restrict__ EB,
    float* __restrict__ P,
    const double* __restrict__ E, const double* __restrict__ RSP,
    float* __restrict__ cv, int* __restrict__ cc, float* __restrict__ invRS) {
  const int tid = threadIdx.x;
  if (blockIdx.x < 64) {
    // ---- rows: row sums + exact top-64 (identical math to baseline) ----
    const int k = blockIdx.x;
    __shared__ double redd[256];
    __shared__ ull keys[2048];
    __shared__ ull wbest[4];
    const double* er = E + (size_t)k * DD;
    double psum = 0.0;
    for (int b = tid; b < 313; b += 256) psum += RSP[(size_t)b * NK + k];
    redd[tid] = psum;
    __syncthreads();
    for (int s = 128; s; s >>= 1) {
      if (tid < s) redd[tid] += redd[tid + s];
      __syncthreads();
    }
    const double sumall = redd[0];
    if (tid == 0) invRS[k] = (float)(1.0 / sumall);
    float tv[8]; int tc[8];
#pragma unroll
    for (int s = 0; s < 8; ++s) { tv[s] = -1.f; tc[s] = 0; }
    for (int d = tid; d < DD; d += 256) {
      float svv = (float)(er[d] / sumall);   // same bits as samples (f32)
      if (svv > tv[7]) {
        float cvr = svv; int ccr = d;
#pragma unroll
        for (int s = 0; s < 8; ++s) {
          bool sw = cvr > tv[s];
          float nv = sw ? cvr : tv[s]; int nc = sw ? ccr : tc[s];
          cvr = sw ? tv[s] : cvr; ccr = sw ? tc[s] : ccr;
          tv[s] = nv; tc[s] = nc;
        }
      }
    }
#pragma unroll
    for (int s = 0; s < 8; ++s)
      keys[(tid << 3) + s] = (((ull)__float_as_uint(tv[s])) << 32)
                           | ((ull)(uint32_t)(32767 - tc[s]) << 11)
                           | ((ull)tid << 3) | (ull)s;
    __syncthreads();
    for (int t = 0; t < NK; ++t) {
      ull best = 0;
#pragma unroll
      for (int s = 0; s < 8; ++s) { ull kk = keys[(tid << 3) + s]; if (kk > best) best = kk; }
#pragma unroll
      for (int off = 32; off; off >>= 1) { ull o = __shfl_xor(best, off, 64); if (o > best) best = o; }
      if ((tid & 63) == 0) wbest[tid >> 6] = best;
      __syncthreads();
      ull win = wbest[0];
#pragma unroll
      for (int wI = 1; wI < 4; ++wI) if (wbest[wI] > win) win = wbest[wI];
      const uint32_t lo = (uint32_t)win;
      const int slot = lo & 7;
      const int owner = (lo >> 3) & 255;
      const int col = 32767 - (int)(lo >> 11);
      if (tid == 0) {
        cv[(k << 6) + t] = __uint_as_float((uint32_t)(win >> 32));
        cc[(k << 6) + t] = col;
      }
      if (tid == owner) keys[(owner << 3) + slot] = 0;
      __syncthreads();
    }
    return;
  }
  // ---- GEMM: P[ksp] = X @ bf16(e)^T, 16x16x32 bf16 MFMA ----
  const int bx2 = blockIdx.x - 64;
  const int ksp = bx2 >> 6;         // ksp-major: 64 consecutive blocks share EB slice
  const int by = bx2 & 63;
  const int lane = tid & 63;
  const int wv = tid >> 6;
  const int m16 = lane & 15;
  const int kq = lane >> 4;         // 0..3
  const int mRow = by * 64 + wv * 16 + m16;
  const float* xq = X + (size_t)mRow * DD + ksp * 32 + kq * 8;
  const ushort* bq = EB + (size_t)m16 * DD + ksp * 32 + kq * 8;
  f32x4 acc[4] = {{0,0,0,0},{0,0,0,0},{0,0,0,0},{0,0,0,0}};
  const int jN = (625 - ksp + KS - 1) / KS;   // 40 for ksp==0, else 39

#define LOADBUF(xa, xb, bn, j) { \
    const int o_ = (j) * (KS * 32); \
    xa = *(const float4*)(xq + o_); \
    xb = *(const float4*)(xq + o_ + 4); \
    bn##0 = *(const uint4*)(bq + o_); \
    bn##1 = *(const uint4*)(bq + 16 * DD + o_); \
    bn##2 = *(const uint4*)(bq + 32 * DD + o_); \
    bn##3 = *(const uint4*)(bq + 48 * DD + o_); }

#define COMPUTEBUF(xa, xb, bn) { \
    uint32_t t0=__float_as_uint(xa.x), t1=__float_as_uint(xa.y), t2=__float_as_uint(xa.z), t3=__float_as_uint(xa.w); \
    uint32_t t4=__float_as_uint(xb.x), t5=__float_as_uint(xb.y), t6=__float_as_uint(xb.z), t7=__float_as_uint(xb.w); \
    t0=(t0+0x7FFFu+((t0>>16)&1u))>>16; t1=(t1+0x7FFFu+((t1>>16)&1u))>>16; \
    t2=(t2+0x7FFFu+((t2>>16)&1u))>>16; t3=(t3+0x7FFFu+((t3>>16)&1u))>>16; \
    t4=(t4+0x7FFFu+((t4>>16)&1u))>>16; t5=(t5+0x7FFFu+((t5>>16)&1u))>>16; \
    t6=(t6+0x7FFFu+((t6>>16)&1u))>>16; t7=(t7+0x7FFFu+((t7>>16)&1u))>>16; \
    union { uint32_t u[4]; short8 v; } A_; \
    A_.u[0]=t0|(t1<<16); A_.u[1]=t2|(t3<<16); A_.u[2]=t4|(t5<<16); A_.u[3]=t6|(t7<<16); \
    union { uint4 q; short8 v; } Q0_, Q1_, Q2_, Q3_; \
    Q0_.q = bn##0; Q1_.q = bn##1; Q2_.q = bn##2; Q3_.q = bn##3; \
    acc[0] = __builtin_amdgcn_mfma_f32_16x16x32_bf16(A_.v, Q0_.v, acc[0], 0, 0, 0); \
    acc[1] = __builtin_amdgcn_mfma_f32_16x16x32_bf16(A_.v, Q1_.v, acc[1], 0, 0, 0); \
    acc[2] = __builtin_amdgcn_mfma_f32_16x16x32_bf16(A_.v, Q2_.v, acc[2], 0, 0, 0); \
    acc[3] = __builtin_amdgcn_mfma_f32_16x16x32_bf16(A_.v, Q3_.v, acc[3], 0, 0, 0); }

  float4 xaA, xbA, xaB, xbB, xaC, xbC, xaD, xbD;
  uint4 bA0, bA1, bA2, bA3, bB0, bB1, bB2, bB3;
  uint4 bC0, bC1, bC2, bC3, bD0, bD1, bD2, bD3;
  LOADBUF(xaA, xbA, bA, 0);        // jN >= 39, so j = 0..3 always valid
  LOADBUF(xaB, xbB, bB, 1);
  LOADBUF(xaC, xbC, bC, 2);
  LOADBUF(xaD, xbD, bD, 3);
  int j = 0;
  for (; j + 4 < jN; j += 4) {
    COMPUTEBUF(xaA, xbA, bA);
    LOADBUF(xaA, xbA, bA, j + 4);
    COMPUTEBUF(xaB, xbB, bB);
    if (j + 5 < jN) { LOADBUF(xaB, xbB, bB, j + 5); }
    COMPUTEBUF(xaC, xbC, bC);
    if (j + 6 < jN) { LOADBUF(xaC, xbC, bC, j + 6); }
    COMPUTEBUF(xaD, xbD, bD);
    if (j + 7 < jN) { LOADBUF(xaD, xbD, bD, j + 7); }
  }
  COMPUTEBUF(xaA, xbA, bA);
  if (j + 1 < jN) { COMPUTEBUF(xaB, xbB, bB); }
  if (j + 2 < jN) { COMPUTEBUF(xaC, xbC, bC); }
  if (j + 3 < jN) { COMPUTEBUF(xaD, xbD, bD); }
#undef LOADBUF
#undef COMPUTEBUF

  float* pp = P + (size_t)ksp * YN;
  const int rBase = by * 64 + wv * 16 + kq * 4;
#pragma unroll
  for (int nt = 0; nt < 4; ++nt)
#pragma unroll
    for (int r = 0; r < 4; ++r)
      pp[(size_t)(rBase + r) * 64 + nt * 16 + m16] = acc[nt][r];
}

// ---------------- K3: fused greedy (block 0) + Y reduction (blocks 1..256) --
__global__ __launch_bounds__(256) void k_tail(
    const float* __restrict__ cv, const int* __restrict__ cc,
    const float* __restrict__ temp, const float* __restrict__ P,
    const float* __restrict__ invRS, float* __restrict__ out) {
  const int tid = threadIdx.x;
  if (blockIdx.x == 0) {
    // greedy bipartite argmax-and-mask; register heads + f32 ballot argmax.
    __shared__ float vf[NK * NK];
    __shared__ int cf[NK * NK];
    __shared__ alignas(16) unsigned char used[DD];
    for (int i = tid; i < 1250; i += 256) ((int4*)used)[i] = make_int4(0, 0, 0, 0);
    for (int i = tid; i < 1024; i += 256) {
      ((float4*)vf)[i] = ((const float4*)cv)[i];
      ((int4*)cf)[i] = ((const int4*)cc)[i];
    }
    __syncthreads();
    if (tid >= 64) return;          // wave 0 only past this point (no barriers)
    const int lane = tid;           // = row k
    int ptr = 0;
    float hv = vf[lane << 6];       // current head (row's best unused col)
    int hc = cf[lane << 6];
    bool done = false;
    for (int t = 0; t < NK; ++t) {
      const float v = done ? -1.f : hv;
      float m = v;
#pragma unroll
      for (int off = 32; off; off >>= 1) m = fmaxf(m, __shfl_xor(m, off, 64));
      const ull mask = __ballot(v == m);         // ties -> smallest row wins
      const int row = __ffsll(mask) - 1;         // == flat-argmax tie-break
      const int col = __shfl(hc, row, 64);
      if (lane == row) done = true;
      if (lane == 0) {
        used[col] = 1;
        out[YN + (size_t)row * DD + col] = 1.0f;
      }
      asm volatile("s_waitcnt lgkmcnt(0)" ::: "memory");  // used[] visible
      if (!done && hc == col) {     // advance past used cols (lazy skip)
        ++ptr;
        while (ptr < NK) {
          hc = cf[(lane << 6) + ptr];
          if (!used[hc]) break;
          ++ptr;
        }
        if (ptr < NK) hv = vf[(lane << 6) + ptr];
        else { hv = -2.f; hc = 0; } // exhausted (cannot occur in practice)
      }
    }
    if (lane == 0) out[TOTN - 1] = fmaxf(0.1f, temp[0] * 0.99999f);
    return;
  }
  // ---- Y = (sum of KS partials) * invRS[col] (identical math to baseline) --
  const int i = (blockIdx.x - 1) * 256 + tid;
  float4 a = ((const float4*)P)[i];
#pragma unroll
  for (int j = 1; j < KS; ++j) {
    const float4 b = ((const float4*)(P + (size_t)j * YN))[i];
    a.x += b.x; a.y += b.y; a.z += b.z; a.w += b.w;
  }
  const float4 irs = *(const float4*)(invRS + ((i * 4) & 63));
  a.x *= irs.x; a.y *= irs.y; a.z *= irs.z; a.w *= irs.w;
  ((float4*)out)[i] = a;
}

extern "C" void kernel_launch(void* const* d_in, const int* in_sizes, int n_in,
                              void* d_out, int out_size, void* d_ws, size_t ws_size,
                              hipStream_t stream) {
  (void)in_sizes; (void)n_in; (void)out_size; (void)ws_size;
  const float* X = (const float*)d_in[0];
  const float* uu = (const float*)d_in[1];
  const float* tw = (const float*)d_in[2];
  const float* temp = (const float*)d_in[3];
  float* out = (float*)d_out;
  char* W = (char*)d_ws;
  double* E   = (double*)(W + E_OFF);
  double* RSP = (double*)(W + RSP_OFF);
  float*  CV  = (float*)(W + CV_OFF);
  int*    CC  = (int*)(W + CC_OFF);
  ushort* EB  = (ushort*)(W + EB_OFF);
  float*  IRS = (float*)(W + IRS_OFF);
  float*  P   = (float*)(W + P_OFF);

  hipLaunchKernelGGL(k_z, dim3(313), dim3(256), 0, stream, uu, tw, temp, E, EB, RSP, out + YN);
  hipLaunchKernelGGL(k_gr, dim3(64 + KS * 64), dim3(256), 0, stream, X, EB, P, E, RSP, CV, CC, IRS);
  hipLaunchKernelGGL(k_tail, dim3(257), dim3(256), 0, stream, CV, CC, temp, P, IRS, out);
}

// Round 4
// 557.551 us; speedup vs baseline: 1.1849x; 1.0028x over previous
//
#include <hip/hip_runtime.h>
#include <stdint.h>
#include <math.h>

typedef unsigned long long ull;
typedef __attribute__((ext_vector_type(8))) short short8;
typedef __attribute__((ext_vector_type(4))) float f32x4;

#define DD 20000
#define NK 64
#define NB 4096
#define YN (NB * NK)              // 262144
#define TOTN (YN + NK * DD + 1)   // 1542145
#define KS 15                     // split-K factor: 64 rows + 15*64 gemm = 1024 blocks
                                  // == one full dispatch generation at 4 blocks/CU
                                  // (KS=16 -> 1088 blocks -> 64-block straggler gen
                                  //  at 6% utilization for ~T_b; KS=15 kills it)

// ws byte offsets (~28.7 MB used)
#define E_OFF   0u                 // f64 e = exp(z) [64][20000]
#define RSP_OFF 10240000u          // f64 row partial sums [313][64]
#define CV_OFF  10400256u          // f32 top-64 vals [64][64]
#define CC_OFF  10416640u          // i32 top-64 cols [64][64]
#define EB_OFF  10433024u          // bf16 e [64][20000] (ushort)
#define IRS_OFF 12993024u          // f32 1/rowsum [64]
#define P_OFF   12993280u          // f32 GEMM partials [KS][4096][64]

// ---------------- threefry2x32, JAX partitionable scheme ----------------
__device__ __forceinline__ uint32_t tf_bits(uint32_t j) {
  const uint32_t k0 = 0u, k1 = 42u;
  const uint32_t k2 = 0x1BD11BDAu ^ k0 ^ k1;
  uint32_t x0 = k0;
  uint32_t x1 = j + k1;
#define TFR(r) { x0 += x1; x1 = (x1 << r) | (x1 >> (32 - r)); x1 ^= x0; }
  TFR(13) TFR(15) TFR(26) TFR(6)
  x0 += k1; x1 += k2 + 1u;
  TFR(17) TFR(29) TFR(16) TFR(24)
  x0 += k2; x1 += k0 + 2u;
  TFR(13) TFR(15) TFR(26) TFR(6)
  x0 += k0; x1 += k1 + 3u;
  TFR(17) TFR(29) TFR(16) TFR(24)
  x0 += k1; x1 += k2 + 4u;
  TFR(13) TFR(15) TFR(26) TFR(6)
  x0 += k2; x1 += k0 + 5u;
#undef TFR
  return x0 ^ x1;
}

// ---------------- K1: e = exp((log(10*clip(sm64(u@W))) + gumbel)/nt) --------
__global__ __launch_bounds__(256) void k_z(
    const float* __restrict__ uu, const float* __restrict__ tw,
    const float* __restrict__ temp, double* __restrict__ E,
    ushort* __restrict__ EB, double* __restrict__ RSP,
    float* __restrict__ disc) {
  __shared__ double tile[NK][65];   // [k][dl], +1 pad
  __shared__ double psumw[4][NK];
  const int tid = threadIdx.x;
  const int lane = tid & 63;      // = k
  const int wv = tid >> 6;
  const int d0 = blockIdx.x * 64;
  const float nt = fmaxf(0.1f, temp[0] * 0.99999f);
  float w[10];
#pragma unroll
  for (int i = 0; i < 10; ++i) w[i] = tw[i * NK + lane];
  double psum = 0.0;
  for (int it = 0; it < 16; ++it) {
    const int dl = wv * 16 + it;
    const int d = d0 + dl;
    double e = 0.0;
    if (d < DD) {  // wave-uniform branch
      float m = 0.f;
#pragma unroll
      for (int i = 0; i < 10; ++i) m = fmaf(uu[d * 10 + i], w[i], m);
      float mx = m;
#pragma unroll
      for (int off = 32; off; off >>= 1) mx = fmaxf(mx, __shfl_xor(mx, off, 64));
      double ee = exp((double)(m - mx));
      double ssum = ee;
#pragma unroll
      for (int off = 32; off; off >>= 1) ssum += __shfl_xor(ssum, off, 64);
      float al = (float)(ee / ssum);
      float c = fminf(fmaxf(al, 1e-7f), 0.9999999f);
      float lg = (float)log((double)(10.0f * c));
      const uint32_t bits = tf_bits((uint32_t)(lane * DD + d));
      float uf = __uint_as_float((bits >> 9) | 0x3f800000u) - 1.0f;
      float uv = fmaxf(1e-7f, uf * (1.0f - 1e-7f) + 1e-7f);
      float g = (float)(-log(-log((double)uv)));
      float z = (lg + g) / nt;     // z in [-1.7, 1.9] -> no max-sub needed
      e = exp((double)z);
    }
    tile[lane][dl] = e;
    psum += e;
  }
  psumw[wv][lane] = psum;
  __syncthreads();
  for (int r0 = 0; r0 < NK; r0 += 4) {
    const int r = r0 + wv;
    const int d = d0 + lane;
    if (d < DD) {
      const double ev = tile[r][lane];
      E[(size_t)r * DD + d] = ev;
      const float ef = (float)ev;
      uint32_t ub = __float_as_uint(ef);
      EB[(size_t)r * DD + d] = (ushort)((ub + 0x7FFFu + ((ub >> 16) & 1u)) >> 16);
    }
  }
  if (wv == 0) {
    double s = psumw[0][lane] + psumw[1][lane] + psumw[2][lane] + psumw[3][lane];
    RSP[(size_t)blockIdx.x * NK + lane] = s;
  }
  // zero the discrete slice: cols [d0, d0+64) x 64 rows, float4 stores
  const int cg = tid & 15;         // col group (4 cols)
  const int r0 = tid >> 4;         // 0..15
  if (d0 + cg * 4 < DD) {
    for (int r = r0; r < NK; r += 16)
      *(float4*)(disc + (size_t)r * DD + d0 + cg * 4) = make_float4(0.f, 0.f, 0.f, 0.f);
  }
}

// ---------------- K2: fused rows (blocks 0..63) + split-K GEMM (64..1023) ---
// Round-1 codegen exactly (3-deep register prefetch, no launch-bounds min,
// no atomics). Only the grid/KS changed: 1024 blocks = one generation.
__global__ __launch_bounds__(256) void k_gr(
    const float* __restrict__ X, const ushort* __restrict__ EB,
    float* __restrict__ P,
    const double* __restrict__ E, const double* __restrict__ RSP,
    float* __restrict__ cv, int* __restrict__ cc, float* __restrict__ invRS) {
  const int tid = threadIdx.x;
  if (blockIdx.x < 64) {
    // ---- rows: row sums + exact top-64 (identical math to baseline) ----
    const int k = blockIdx.x;
    __shared__ double redd[256];
    __shared__ ull keys[2048];
    __shared__ ull wbest[4];
    const double* er = E + (size_t)k * DD;
    double psum = 0.0;
    for (int b = tid; b < 313; b += 256) psum += RSP[(size_t)b * NK + k];
    redd[tid] = psum;
    __syncthreads();
    for (int s = 128; s; s >>= 1) {
      if (tid < s) redd[tid] += redd[tid + s];
      __syncthreads();
    }
    const double sumall = redd[0];
    if (tid == 0) invRS[k] = (float)(1.0 / sumall);
    float tv[8]; int tc[8];
#pragma unroll
    for (int s = 0; s < 8; ++s) { tv[s] = -1.f; tc[s] = 0; }
    for (int d = tid; d < DD; d += 256) {
      float svv = (float)(er[d] / sumall);   // same bits as samples (f32)
      if (svv > tv[7]) {
        float cvr = svv; int ccr = d;
#pragma unroll
        for (int s = 0; s < 8; ++s) {
          bool sw = cvr > tv[s];
          float nv = sw ? cvr : tv[s]; int nc = sw ? ccr : tc[s];
          cvr = sw ? tv[s] : cvr; ccr = sw ? tc[s] : ccr;
          tv[s] = nv; tc[s] = nc;
        }
      }
    }
#pragma unroll
    for (int s = 0; s < 8; ++s)
      keys[(tid << 3) + s] = (((ull)__float_as_uint(tv[s])) << 32)
                           | ((ull)(uint32_t)(32767 - tc[s]) << 11)
                           | ((ull)tid << 3) | (ull)s;
    __syncthreads();
    for (int t = 0; t < NK; ++t) {
      ull best = 0;
#pragma unroll
      for (int s = 0; s < 8; ++s) { ull kk = keys[(tid << 3) + s]; if (kk > best) best = kk; }
#pragma unroll
      for (int off = 32; off; off >>= 1) { ull o = __shfl_xor(best, off, 64); if (o > best) best = o; }
      if ((tid & 63) == 0) wbest[tid >> 6] = best;
      __syncthreads();
      ull win = wbest[0];
#pragma unroll
      for (int wI = 1; wI < 4; ++wI) if (wbest[wI] > win) win = wbest[wI];
      const uint32_t lo = (uint32_t)win;
      const int slot = lo & 7;
      const int owner = (lo >> 3) & 255;
      const int col = 32767 - (int)(lo >> 11);
      if (tid == 0) {
        cv[(k << 6) + t] = __uint_as_float((uint32_t)(win >> 32));
        cc[(k << 6) + t] = col;
      }
      if (tid == owner) keys[(owner << 3) + slot] = 0;
      __syncthreads();
    }
    return;
  }
  // ---- GEMM: P[ksp] = X @ bf16(e)^T, 16x16x32 bf16 MFMA ----
  const int bx2 = blockIdx.x - 64;
  const int ksp = bx2 >> 6;         // ksp-major: 64 consecutive blocks share EB slice
  const int by = bx2 & 63;
  const int lane = tid & 63;
  const int wv = tid >> 6;
  const int m16 = lane & 15;
  const int kq = lane >> 4;         // 0..3
  const int mRow = by * 64 + wv * 16 + m16;
  const float* xq = X + (size_t)mRow * DD + ksp * 32 + kq * 8;
  const ushort* bq = EB + (size_t)m16 * DD + ksp * 32 + kq * 8;
  f32x4 acc[4] = {{0,0,0,0},{0,0,0,0},{0,0,0,0},{0,0,0,0}};
  const int jN = (625 - ksp + KS - 1) / KS;   // 42 for ksp<=9, else 41

#define LOADBUF(xa, xb, bn, j) { \
    const int o_ = (j) * (KS * 32); \
    xa = *(const float4*)(xq + o_); \
    xb = *(const float4*)(xq + o_ + 4); \
    bn##0 = *(const uint4*)(bq + o_); \
    bn##1 = *(const uint4*)(bq + 16 * DD + o_); \
    bn##2 = *(const uint4*)(bq + 32 * DD + o_); \
    bn##3 = *(const uint4*)(bq + 48 * DD + o_); }

#define COMPUTEBUF(xa, xb, bn) { \
    uint32_t t0=__float_as_uint(xa.x), t1=__float_as_uint(xa.y), t2=__float_as_uint(xa.z), t3=__float_as_uint(xa.w); \
    uint32_t t4=__float_as_uint(xb.x), t5=__float_as_uint(xb.y), t6=__float_as_uint(xb.z), t7=__float_as_uint(xb.w); \
    t0=(t0+0x7FFFu+((t0>>16)&1u))>>16; t1=(t1+0x7FFFu+((t1>>16)&1u))>>16; \
    t2=(t2+0x7FFFu+((t2>>16)&1u))>>16; t3=(t3+0x7FFFu+((t3>>16)&1u))>>16; \
    t4=(t4+0x7FFFu+((t4>>16)&1u))>>16; t5=(t5+0x7FFFu+((t5>>16)&1u))>>16; \
    t6=(t6+0x7FFFu+((t6>>16)&1u))>>16; t7=(t7+0x7FFFu+((t7>>16)&1u))>>16; \
    union { uint32_t u[4]; short8 v; } A_; \
    A_.u[0]=t0|(t1<<16); A_.u[1]=t2|(t3<<16); A_.u[2]=t4|(t5<<16); A_.u[3]=t6|(t7<<16); \
    union { uint4 q; short8 v; } Q0_, Q1_, Q2_, Q3_; \
    Q0_.q = bn##0; Q1_.q = bn##1; Q2_.q = bn##2; Q3_.q = bn##3; \
    acc[0] = __builtin_amdgcn_mfma_f32_16x16x32_bf16(A_.v, Q0_.v, acc[0], 0, 0, 0); \
    acc[1] = __builtin_amdgcn_mfma_f32_16x16x32_bf16(A_.v, Q1_.v, acc[1], 0, 0, 0); \
    acc[2] = __builtin_amdgcn_mfma_f32_16x16x32_bf16(A_.v, Q2_.v, acc[2], 0, 0, 0); \
    acc[3] = __builtin_amdgcn_mfma_f32_16x16x32_bf16(A_.v, Q3_.v, acc[3], 0, 0, 0); }

  float4 xaA, xbA, xaB, xbB, xaC, xbC;
  uint4 bA0, bA1, bA2, bA3, bB0, bB1, bB2, bB3, bC0, bC1, bC2, bC3;
  LOADBUF(xaA, xbA, bA, 0);        // jN >= 41, so j = 0,1,2 always valid
  LOADBUF(xaB, xbB, bB, 1);
  LOADBUF(xaC, xbC, bC, 2);
  int j = 0;
  for (; j + 3 < jN; j += 3) {
    COMPUTEBUF(xaA, xbA, bA);
    LOADBUF(xaA, xbA, bA, j + 3);
    COMPUTEBUF(xaB, xbB, bB);
    if (j + 4 < jN) { LOADBUF(xaB, xbB, bB, j + 4); }
    COMPUTEBUF(xaC, xbC, bC);
    if (j + 5 < jN) { LOADBUF(xaC, xbC, bC, j + 5); }
  }
  COMPUTEBUF(xaA, xbA, bA);
  if (j + 1 < jN) { COMPUTEBUF(xaB, xbB, bB); }
  if (j + 2 < jN) { COMPUTEBUF(xaC, xbC, bC); }
#undef LOADBUF
#undef COMPUTEBUF

  float* pp = P + (size_t)ksp * YN;
  const int rBase = by * 64 + wv * 16 + kq * 4;
#pragma unroll
  for (int nt = 0; nt < 4; ++nt)
#pragma unroll
    for (int r = 0; r < 4; ++r)
      pp[(size_t)(rBase + r) * 64 + nt * 16 + m16] = acc[nt][r];
}

// ---------------- K3: fused greedy (block 0) + Y reduction (blocks 1..256) --
__global__ __launch_bounds__(256) void k_tail(
    const float* __restrict__ cv, const int* __restrict__ cc,
    const float* __restrict__ temp, const float* __restrict__ P,
    const float* __restrict__ invRS, float* __restrict__ out) {
  const int tid = threadIdx.x;
  if (blockIdx.x == 0) {
    // greedy bipartite argmax-and-mask; register heads + f32 ballot argmax.
    __shared__ float vf[NK * NK];
    __shared__ int cf[NK * NK];
    __shared__ alignas(16) unsigned char used[DD];
    for (int i = tid; i < 1250; i += 256) ((int4*)used)[i] = make_int4(0, 0, 0, 0);
    for (int i = tid; i < 1024; i += 256) {
      ((float4*)vf)[i] = ((const float4*)cv)[i];
      ((int4*)cf)[i] = ((const int4*)cc)[i];
    }
    __syncthreads();
    if (tid >= 64) return;          // wave 0 only past this point (no barriers)
    const int lane = tid;           // = row k
    int ptr = 0;
    float hv = vf[lane << 6];       // current head (row's best unused col)
    int hc = cf[lane << 6];
    bool done = false;
    for (int t = 0; t < NK; ++t) {
      const float v = done ? -1.f : hv;
      float m = v;
#pragma unroll
      for (int off = 32; off; off >>= 1) m = fmaxf(m, __shfl_xor(m, off, 64));
      const ull mask = __ballot(v == m);         // ties -> smallest row wins
      const int row = __ffsll(mask) - 1;         // == flat-argmax tie-break
      const int col = __shfl(hc, row, 64);
      if (lane == row) done = true;
      if (lane == 0) {
        used[col] = 1;
        out[YN + (size_t)row * DD + col] = 1.0f;
      }
      asm volatile("s_waitcnt lgkmcnt(0)" ::: "memory");  // used[] visible
      if (!done && hc == col) {     // advance past used cols (lazy skip)
        ++ptr;
        while (ptr < NK) {
          hc = cf[(lane << 6) + ptr];
          if (!used[hc]) break;
          ++ptr;
        }
        if (ptr < NK) hv = vf[(lane << 6) + ptr];
        else { hv = -2.f; hc = 0; } // exhausted (cannot occur in practice)
      }
    }
    if (lane == 0) out[TOTN - 1] = fmaxf(0.1f, temp[0] * 0.99999f);
    return;
  }
  // ---- Y = (sum of KS partials) * invRS[col] (identical math to baseline) --
  const int i = (blockIdx.x - 1) * 256 + tid;
  float4 a = ((const float4*)P)[i];
#pragma unroll
  for (int j = 1; j < KS; ++j) {
    const float4 b = ((const float4*)(P + (size_t)j * YN))[i];
    a.x += b.x; a.y += b.y; a.z += b.z; a.w += b.w;
  }
  const float4 irs = *(const float4*)(invRS + ((i * 4) & 63));
  a.x *= irs.x; a.y *= irs.y; a.z *= irs.z; a.w *= irs.w;
  ((float4*)out)[i] = a;
}

extern "C" void kernel_launch(void* const* d_in, const int* in_sizes, int n_in,
                              void* d_out, int out_size, void* d_ws, size_t ws_size,
                              hipStream_t stream) {
  (void)in_sizes; (void)n_in; (void)out_size; (void)ws_size;
  const float* X = (const float*)d_in[0];
  const float* uu = (const float*)d_in[1];
  const float* tw = (const float*)d_in[2];
  const float* temp = (const float*)d_in[3];
  float* out = (float*)d_out;
  char* W = (char*)d_ws;
  double* E   = (double*)(W + E_OFF);
  double* RSP = (double*)(W + RSP_OFF);
  float*  CV  = (float*)(W + CV_OFF);
  int*    CC  = (int*)(W + CC_OFF);
  ushort* EB  = (ushort*)(W + EB_OFF);
  float*  IRS = (float*)(W + IRS_OFF);
  float*  P   = (float*)(W + P_OFF);

  hipLaunchKernelGGL(k_z, dim3(313), dim3(256), 0, stream, uu, tw, temp, E, EB, RSP, out + YN);
  hipLaunchKernelGGL(k_gr, dim3(64 + KS * 64), dim3(256), 0, stream, X, EB, P, E, RSP, CV, CC, IRS);
  hipLaunchKernelGGL(k_tail, dim3(257), dim3(256), 0, stream, CV, CC, temp, P, IRS, out);
}